// Round 8
// baseline (781.900 us; speedup 1.0000x reference)
//
#include <hip/hip_runtime.h>

// Fused StyleGAN2 conv_downsample_2d, f32-VALU, occupancy-optimized.
//   out[n,oc,oh,ow] = sum_c w[c,oc] * y[n,c,2oh,2ow]
//   y = separable FIR {1,3,3,1}/8 (vert) x {1,3,3,1}/8 (horiz), pad=1
//
// Design ledger:
//  - bf16 MFMA: ~3.6% per-term noise on this op (rounds 2/3/5), precision-
//    split-invariant -> fails 0.4325 threshold. f32 VALU path.
//  - Round 7: 16 waves/CU cap was REGISTER-bound (64 arch VGPR + 64-float acc
//    in unified file ~ 128 total). Fix: acc 8x4 = 32 regs -> total ~64 ->
//    32 waves/CU (4 blocks x 512thr). __launch_bounds__(512,8) cap 64 VGPR;
//    need ~60 so no round-6-style spill (tripwire: WRITE_SIZE >> 2.7e5 KB).
//  - w read from L2/L1 directly (128 KB, block-invariant): kills w_s staging
//    and halves GEMM LDS traffic (LDS+VALU were co-saturated at 1 B/FMA).
//  - Vertical FIR fused into staging -> v_s only; LDS 66 KB -> 14 KB.
//
// Block: 512 thr; tile = 256 oc x (8 oh x 8 ow); K-chunks of 16 channels.

#define CH 16
#define VPITCH 19              // v_s row pitch (floats, odd)
#define VCSTR  (8 * VPITCH)    // 152 per channel
#define YPITCH 68              // y_s per-channel pitch (64 sp + 4 pad)

__global__ __launch_bounds__(512, 8)
void fused_downconv_f32v3(const float* __restrict__ x, const float* __restrict__ w,
                          float* __restrict__ out) {
    __shared__ __align__(16) float v_s[CH * VCSTR];   // 9728 B
    __shared__ __align__(16) float y_s[CH * YPITCH];  // 4352 B  (total 14080 B)

    const int tid  = threadIdx.x;
    const int oc_g = tid >> 4;    // 0..31 -> oc block of 8
    const int sp_g = tid & 15;    // 0..15 -> sp block of 4

    const int ow0 = blockIdx.x * 8;
    const int oh0 = blockIdx.y * 8;
    const int n   = blockIdx.z;

    float acc[8][4];
    #pragma unroll
    for (int i = 0; i < 8; i++)
        #pragma unroll
        for (int j = 0; j < 4; j++) acc[i][j] = 0.f;

    const int cbase = 2 * ow0 - 1;
    // interior blocks need no bounds checks: cl in [15,496], rows in [15,496]
    const bool interior = (blockIdx.x >= 1) && (blockIdx.x <= 30) &&
                          (blockIdx.y >= 1) && (blockIdx.y <= 30);

    for (int c0 = 0; c0 < 128; c0 += CH) {
        // ---- stage v: vertical FIR fused; 16ch x 8ohl x 18col points ----
        {
            const float* xn = x + ((size_t)(n * 128 + c0)) * 262144;
            for (int i = tid; i < CH * 144; i += 512) {
                int cc  = i / 144;
                int rem = i - cc * 144;
                int ohl = rem / 18;
                int col = rem - ohl * 18;
                int cl  = cbase + col;
                int rb  = 2 * (oh0 + ohl) - 1;
                float s0, s1, s2, s3;
                if (interior) {
                    const float* xp = xn + (size_t)cc * 262144 + (size_t)rb * 512 + cl;
                    s0 = xp[0]; s1 = xp[512]; s2 = xp[1024]; s3 = xp[1536];
                } else {
                    const float* xp = xn + (size_t)cc * 262144;
                    bool cok = (unsigned)cl < 512u;
                    s0 = (cok && (unsigned)(rb + 0) < 512u) ? xp[(long)(rb + 0) * 512 + cl] : 0.f;
                    s1 = (cok && (unsigned)(rb + 1) < 512u) ? xp[(long)(rb + 1) * 512 + cl] : 0.f;
                    s2 = (cok && (unsigned)(rb + 2) < 512u) ? xp[(long)(rb + 2) * 512 + cl] : 0.f;
                    s3 = (cok && (unsigned)(rb + 3) < 512u) ? xp[(long)(rb + 3) * 512 + cl] : 0.f;
                }
                v_s[cc * VCSTR + ohl * VPITCH + col] =
                    0.125f * (s0 + s3) + 0.375f * (s1 + s2);
            }
        }
        __syncthreads();

        // ---- y phase: horizontal FIR; 16ch x 64sp points, 2 per thread ----
        for (int i = tid; i < CH * 64; i += 512) {
            int cc  = i >> 6;
            int s   = i & 63;
            int ohl = s >> 3;
            int owl = s & 7;
            const float* vp = &v_s[cc * VCSTR + ohl * VPITCH + 2 * owl];
            y_s[cc * YPITCH + s] = 0.125f * (vp[0] + vp[3]) + 0.375f * (vp[1] + vp[2]);
        }
        __syncthreads();

        // ---- GEMM: 8 oc x 4 sp register tile; w from L2/L1, y from LDS ----
        {
            const float* wp = w + (size_t)c0 * 256 + oc_g * 8;
            #pragma unroll
            for (int cc = 0; cc < CH; cc++) {
                float4 y4 = *(const float4*)&y_s[cc * YPITCH + sp_g * 4];
                float4 wa = *(const float4*)&wp[cc * 256];
                float4 wb = *(const float4*)&wp[cc * 256 + 4];
                float wv[8] = {wa.x, wa.y, wa.z, wa.w, wb.x, wb.y, wb.z, wb.w};
                float yv[4] = {y4.x, y4.y, y4.z, y4.w};
                #pragma unroll
                for (int i = 0; i < 8; i++)
                    #pragma unroll
                    for (int j = 0; j < 4; j++)
                        acc[i][j] += wv[i] * yv[j];
            }
        }
        __syncthreads();   // before next chunk overwrites v_s/y_s
    }

    // ---- epilogue: sp = sp_g*4 + j -> oh_l = sp_g>>1, ow = (sp_g&1)*4 + j ----
    {
        const int oh_l = sp_g >> 1;
        const int ow4  = (sp_g & 1) * 4;
        const size_t base = (((size_t)n * 256 + (size_t)oc_g * 8) * 256
                             + (size_t)(oh0 + oh_l)) * 256 + ow0 + ow4;
        #pragma unroll
        for (int i = 0; i < 8; i++) {
            float4 v = make_float4(acc[i][0], acc[i][1], acc[i][2], acc[i][3]);
            *(float4*)&out[base + (size_t)i * 65536] = v;
        }
    }
}

extern "C" void kernel_launch(void* const* d_in, const int* in_sizes, int n_in,
                              void* d_out, int out_size, void* d_ws, size_t ws_size,
                              hipStream_t stream) {
    const float* x = (const float*)d_in[0];
    const float* w = (const float*)d_in[1];
    float* out = (float*)d_out;

    dim3 grid(32, 32, 4);   // ow-tiles(8), oh-tiles(8), n
    dim3 block(512);
    hipLaunchKernelGGL(fused_downconv_f32v3, grid, block, 0, stream, x, w, out);
}

// Round 9
// 436.063 us; speedup vs baseline: 1.7931x; 1.7931x over previous
//
#include <hip/hip_runtime.h>

// Fused StyleGAN2 conv_downsample_2d, f32-VALU, software-pipelined (T14).
//   out[n,oc,oh,ow] = sum_c w[c,oc] * y[n,c,2oh,2ow]
//   y = separable FIR {1,3,3,1}/8 (vert) x {1,3,3,1}/8 (horiz), pad=1
//
// Design ledger:
//  - bf16 MFMA: ~3.6% per-term noise on this op (rounds 2/3/5) -> fails
//    0.4325 threshold. f32 VALU path.
//  - NEVER pass __launch_bounds__ min-waves arg: rounds 6 & 8 both spilled
//    (WRITE_SIZE 0.9-2.5 GB vs 262 MB output). Plain (512) -> no spill (r7).
//  - Occupancy is not binding (r8: 87% occ, slower). r7 is stall-bound:
//    phases serialized behind barriers. This round: T14 prefetch -> regs
//    during y+GEMM phases; w read from L1/L2 in GEMM (kills w_s staging and
//    halves GEMM LDS traffic); 2 barriers/chunk instead of 3.
//  - Stage RAW x (each byte fetched once); fused-v staging re-reads x 2x (r8).
//
// Block: 512 thr; tile = 256 oc x (8 oh x 16 ow); K-chunks of 16 channels.
// Grid (16, 32, 4).

#define CH   16
#define PWP  35                // x_s row pitch (odd)
#define CSTR (18 * PWP + 1)    // 631 floats per channel (odd)
#define YPIT 144               // y_s per-channel pitch

__device__ __forceinline__ int yoff(int g) { return g * 8 + ((g >> 2) << 2); }

__global__ __launch_bounds__(512)
void fused_downconv_f32v4(const float* __restrict__ x, const float* __restrict__ w,
                          float* __restrict__ out) {
    __shared__ __align__(16) float x_s[CH * CSTR];   // 40384 B
    __shared__ __align__(16) float y_s[CH * YPIT];   //  9216 B  (49.6 KB total)

    const int tid  = threadIdx.x;
    const int oc_g = tid >> 4;    // 0..31 -> oc block of 8
    const int sp_g = tid & 15;    // 0..15 -> sp block of 8

    const int ow0 = blockIdx.x * 16;
    const int oh0 = blockIdx.y * 8;
    const int n   = blockIdx.z;

    const int rbase = 2 * oh0 - 1;
    const int cbase = 2 * ow0 - 1;
    // interior: all rows rbase..rbase+17 and cols cbase..cbase+33 in [0,512)
    const bool interior = (blockIdx.x >= 1) && (blockIdx.x <= 14) &&
                          (blockIdx.y >= 1) && (blockIdx.y <= 30);

    // staging mapping: pcc = channel, pl = lane within channel; point
    // p = pl + 32k walks the 18x34 patch row-major (pitch 34), k = 0..19.
    const int pcc = tid >> 5;     // 0..15
    const int pl  = tid & 31;     // 0..31

    // y-phase mapping (proven in r7)
    const int yp_cc  = tid >> 5;
    const int yp_ohl = (tid & 31) >> 2;
    const int yp_ow4 = (tid & 3) * 4;
    const int yp_cl0 = yp_ow4 * 2;
    const int yp_g   = yp_ohl * 2 + (yp_ow4 >> 3);
    const int yp_dst = yp_cc * YPIT + yoff(yp_g) + (yp_ow4 & 4);
    const int y_rd   = yoff(sp_g);

    float xr[20];
    float acc[8][8];
    #pragma unroll
    for (int i = 0; i < 8; i++)
        #pragma unroll
        for (int j = 0; j < 8; j++) acc[i][j] = 0.f;

    auto do_prefetch = [&](int c0) {
        const float* xn = x + ((size_t)(n * 128 + c0 + pcc)) * 262144;
        if (interior) {
            const float* g = xn + (size_t)rbase * 512 + (cbase + pl);
            int col = pl;
            #pragma unroll
            for (int k = 0; k < 20; k++) {
                xr[k] = *g;                       // k=19,pl>=4 reads junk (safe addr), never stored
                bool wrap = (col >= 2);           // col+32 >= 34
                col += wrap ? -2 : 32;
                g   += wrap ? 510 : 32;           // (+1 row, -2 col) or +32 col
            }
        } else {
            int col = pl, row = 0;
            #pragma unroll
            for (int k = 0; k < 20; k++) {
                int gr = rbase + row, gc = cbase + col;
                bool ok = ((unsigned)gr < 512u) && ((unsigned)gc < 512u);
                xr[k] = ok ? xn[(size_t)gr * 512 + gc] : 0.f;
                bool wrap = (col >= 2);
                col += wrap ? -2 : 32;
                row += wrap ? 1 : 0;
            }
        }
    };

    do_prefetch(0);

    for (int c0 = 0; c0 < 128; c0 += CH) {
        // ---- write phase: xr -> x_s (row-major pitch PWP per channel) ----
        {
            int la = pcc * CSTR + pl;   // row 0, col pl
            int col = pl;
            #pragma unroll
            for (int k = 0; k < 20; k++) {
                if (k < 19 || pl < 4) x_s[la] = xr[k];   // patch has 612 pts; k19 only pl<4
                bool wrap = (col >= 2);
                col += wrap ? -2 : 32;
                la  += wrap ? 33 : 32;   // +PWP-2 or +32
            }
        }
        __syncthreads();   // x_s ready (also orders prev GEMM y_s reads vs y-write below)

        // ---- prefetch next chunk into regs; latency hides under y+GEMM ----
        if (c0 + CH < 128) do_prefetch(c0 + CH);

        // ---- y phase: separable FIR in registers; 4 y per thread ----
        {
            const int r0 = yp_ohl * 2;
            const float* xb = &x_s[yp_cc * CSTR + r0 * PWP + yp_cl0];
            float colv[10];
            #pragma unroll
            for (int j = 0; j < 10; j++)
                colv[j] = 0.125f * (xb[j] + xb[3 * PWP + j])
                        + 0.375f * (xb[PWP + j] + xb[2 * PWP + j]);
            float4 yv4;
            yv4.x = 0.125f * (colv[0] + colv[3]) + 0.375f * (colv[1] + colv[2]);
            yv4.y = 0.125f * (colv[2] + colv[5]) + 0.375f * (colv[3] + colv[4]);
            yv4.z = 0.125f * (colv[4] + colv[7]) + 0.375f * (colv[5] + colv[6]);
            yv4.w = 0.125f * (colv[6] + colv[9]) + 0.375f * (colv[7] + colv[8]);
            *(float4*)&y_s[yp_dst] = yv4;
        }
        __syncthreads();   // y_s ready

        // ---- GEMM: 8 oc x 8 sp per thread; w from L1/L2, y from LDS ----
        {
            const float* wp = w + (size_t)c0 * 256 + oc_g * 8;
            #pragma unroll 4
            for (int cc = 0; cc < CH; cc++) {
                float4 wa = *(const float4*)&wp[cc * 256];
                float4 wb = *(const float4*)&wp[cc * 256 + 4];
                float4 ya = *(const float4*)&y_s[cc * YPIT + y_rd];
                float4 yb = *(const float4*)&y_s[cc * YPIT + y_rd + 4];
                float wv[8] = {wa.x, wa.y, wa.z, wa.w, wb.x, wb.y, wb.z, wb.w};
                float yv[8] = {ya.x, ya.y, ya.z, ya.w, yb.x, yb.y, yb.z, yb.w};
                #pragma unroll
                for (int i = 0; i < 8; i++)
                    #pragma unroll
                    for (int j = 0; j < 8; j++)
                        acc[i][j] += wv[i] * yv[j];
            }
        }
        // no barrier: next write touches x_s only; y_s reads drain at next
        // __syncthreads (lgkmcnt(0) before s_barrier) before y_s is rewritten
    }

    // ---- epilogue: sp = sp_g*8 + j -> oh_l = sp_g>>1, ow = (sp_g&1)*8 + j ----
    {
        const int oh_l = sp_g >> 1;
        const int owst = (sp_g & 1) * 8;
        const size_t obase = (((size_t)n * 256 + (size_t)oc_g * 8) * 256
                              + (size_t)(oh0 + oh_l)) * 256 + ow0 + owst;
        #pragma unroll
        for (int i = 0; i < 8; i++) {
            float4 v0 = make_float4(acc[i][0], acc[i][1], acc[i][2], acc[i][3]);
            float4 v1 = make_float4(acc[i][4], acc[i][5], acc[i][6], acc[i][7]);
            *(float4*)&out[obase + (size_t)i * 65536]     = v0;
            *(float4*)&out[obase + (size_t)i * 65536 + 4] = v1;
        }
    }
}

extern "C" void kernel_launch(void* const* d_in, const int* in_sizes, int n_in,
                              void* d_out, int out_size, void* d_ws, size_t ws_size,
                              hipStream_t stream) {
    const float* x = (const float*)d_in[0];
    const float* w = (const float*)d_in[1];
    float* out = (float*)d_out;

    dim3 grid(16, 32, 4);   // ow-tiles(16 wide), oh-tiles(8 tall), n
    dim3 block(512);
    hipLaunchKernelGGL(fused_downconv_f32v4, grid, block, 0, stream, x, w, out);
}